// Round 1
// baseline (132.309 us; speedup 1.0000x reference)
//
#include <hip/hip_runtime.h>
#include <math.h>

#define MAXK 256

struct Ws {
    unsigned long long packed[MAXK];   // (q_bits << 32) | ~idx  -> argmax w/ first-index tiebreak
    unsigned int beta_bits[MAXK];      // float-as-uint max (beta > 0)
    float4 xa_q[MAXK];                 // x_a.xyz, q_ak in .w
    float L_beta;
    float Lv_sum;
    float bg_sum;
    int   nb_count;
};

__global__ void k_init(Ws* w) {
    int k = threadIdx.x;
    w->packed[k] = 0ULL;
    w->beta_bits[k] = 0u;
    if (k == 0) { w->L_beta = 0.f; w->Lv_sum = 0.f; w->bg_sum = 0.f; w->nb_count = 0; }
}

__global__ void k_scan(const float* __restrict__ beta, const int* __restrict__ y,
                       const float* __restrict__ qminp, Ws* __restrict__ w, int N) {
    int i = blockIdx.x * blockDim.x + threadIdx.x;
    if (i >= N) return;
    float b = beta[i];
    int yi = y[i];
    if (yi < 0) {
        atomicAdd(&w->bg_sum, b);
        atomicAdd(&w->nb_count, 1);
    } else {
        atomicMax(&w->beta_bits[yi], __float_as_uint(b));
        float a = atanhf(b);
        float q = fmaf(a, a, qminp[0]);
        unsigned long long p = ((unsigned long long)__float_as_uint(q) << 32)
                             | (unsigned long long)(~(unsigned int)i);
        atomicMax(&w->packed[yi], p);
    }
}

__global__ void k_finalize(const float* __restrict__ x, const int* __restrict__ Kp,
                           const float* __restrict__ Sbp, Ws* __restrict__ w) {
    __shared__ float red[256];
    int k = threadIdx.x;
    int K = Kp[0];
    float one_minus = 0.f;
    if (k < K) {
        unsigned long long p = w->packed[k];
        float q; unsigned int idx;
        if (p == 0ULL) { q = 0.f; idx = 0u; }
        else { q = __uint_as_float((unsigned int)(p >> 32)); idx = ~((unsigned int)p); }
        w->xa_q[k] = make_float4(x[idx*3+0], x[idx*3+1], x[idx*3+2], q);
        one_minus = 1.f - __uint_as_float(w->beta_bits[k]);
    }
    red[k] = one_minus;
    __syncthreads();
    for (int s = 128; s > 0; s >>= 1) {
        if (k < s) red[k] += red[k+s];
        __syncthreads();
    }
    if (k == 0) {
        w->L_beta = red[0] / (float)K + Sbp[0] / (float)w->nb_count * w->bg_sum;
    }
}

__global__ void __launch_bounds__(256) k_main(const float* __restrict__ x,
        const float* __restrict__ beta, const int* __restrict__ y,
        const int* __restrict__ Kp, const float* __restrict__ qminp,
        Ws* __restrict__ w, int N) {
    __shared__ float4 s_xa[MAXK];
    __shared__ float red[256];
    int K = Kp[0];
    int t = threadIdx.x;
    if (t < K) s_xa[t] = w->xa_q[t];
    __syncthreads();
    int i = blockIdx.x * blockDim.x + t;
    float contrib = 0.f;
    if (i < N) {
        float x0 = x[i*3+0], x1 = x[i*3+1], x2 = x[i*3+2];
        float b = beta[i];
        int yi = y[i];
        float a = atanhf(b);
        float qi = fmaf(a, a, qminp[0]);
        float acc = 0.f;
        #pragma unroll 4
        for (int k = 0; k < K; ++k) {
            float4 aq = s_xa[k];
            float dx = x0 - aq.x, dy = x1 - aq.y, dz = x2 - aq.z;
            float d = fmaf(dx, dx, fmaf(dy, dy, dz * dz));
            float rep = fmaxf(1.f - d, 0.f);
            float v = (k == yi) ? d : rep;
            acc = fmaf(v, aq.w, acc);
        }
        contrib = acc * qi;
    }
    red[t] = contrib;
    __syncthreads();
    for (int s = 128; s > 0; s >>= 1) {
        if (t < s) red[t] += red[t+s];
        __syncthreads();
    }
    if (t == 0) atomicAdd(&w->Lv_sum, red[0]);
}

__global__ void k_final(const Ws* __restrict__ w, float* __restrict__ out, int N) {
    out[0] = w->L_beta + w->Lv_sum / (float)N;
}

extern "C" void kernel_launch(void* const* d_in, const int* in_sizes, int n_in,
                              void* d_out, int out_size, void* d_ws, size_t ws_size,
                              hipStream_t stream) {
    const float* x     = (const float*)d_in[0];
    const float* beta  = (const float*)d_in[1];
    const int*   y     = (const int*)d_in[2];
    const int*   Kp    = (const int*)d_in[3];
    const float* Sbp   = (const float*)d_in[4];
    const float* qminp = (const float*)d_in[5];
    float* out = (float*)d_out;
    int N = in_sizes[1];
    Ws* w = (Ws*)d_ws;
    int nb = (N + 255) / 256;

    k_init<<<1, 256, 0, stream>>>(w);
    k_scan<<<nb, 256, 0, stream>>>(beta, y, qminp, w, N);
    k_finalize<<<1, 256, 0, stream>>>(x, Kp, Sbp, w);
    k_main<<<nb, 256, 0, stream>>>(x, beta, y, Kp, qminp, w, N);
    k_final<<<1, 1, 0, stream>>>(w, out, N);
}

// Round 2
// 89.415 us; speedup vs baseline: 1.4797x; 1.4797x over previous
//
#include <hip/hip_runtime.h>
#include <math.h>

#define K_MAX 256
#define P1 128   // number of stage-1 partial blocks

struct Ws {
    unsigned long long part_packed[P1 * K_MAX]; // (q_bits<<32)|~idx partial maxes
    unsigned int       part_beta[P1 * K_MAX];   // beta-as-uint partial maxes
    float              part_bg[P1];             // background beta partial sums
    float              part_nb[P1];             // background count partial sums
    float4             xa_q[K_MAX];             // x_a.xyz, q_ak in .w
};

// Stage 1: privatized per-block segment maxima in LDS, plain stores out.
__global__ void __launch_bounds__(256) k_scan(const float* __restrict__ beta,
        const int* __restrict__ y, const float* __restrict__ qminp,
        Ws* __restrict__ w, int N) {
    __shared__ unsigned long long s_packed[K_MAX];
    __shared__ unsigned int s_beta[K_MAX];
    __shared__ float s_red[256];
    int t = threadIdx.x;
    s_packed[t] = 0ULL;
    s_beta[t] = 0u;
    __syncthreads();
    float qmin = qminp[0];
    float bg = 0.f, nb = 0.f;
    for (int i = blockIdx.x * 256 + t; i < N; i += P1 * 256) {
        float b = beta[i];
        int yi = y[i];
        if (yi < 0) {
            bg += b; nb += 1.f;
        } else {
            atomicMax(&s_beta[yi], __float_as_uint(b));
            float a = atanhf(b);
            float q = fmaf(a, a, qmin);
            unsigned long long p = ((unsigned long long)__float_as_uint(q) << 32)
                                 | (unsigned long long)(~(unsigned int)i);
            atomicMax(&s_packed[yi], p);
        }
    }
    __syncthreads();
    w->part_packed[blockIdx.x * K_MAX + t] = s_packed[t];
    w->part_beta[blockIdx.x * K_MAX + t]  = s_beta[t];
    s_red[t] = bg;
    __syncthreads();
    for (int s = 128; s > 0; s >>= 1) { if (t < s) s_red[t] += s_red[t + s]; __syncthreads(); }
    if (t == 0) w->part_bg[blockIdx.x] = s_red[0];
    __syncthreads();
    s_red[t] = nb;
    __syncthreads();
    for (int s = 128; s > 0; s >>= 1) { if (t < s) s_red[t] += s_red[t + s]; __syncthreads(); }
    if (t == 0) w->part_nb[blockIdx.x] = s_red[0];
}

// Stage 2: fold partials, build xa_q table, compute L_beta -> out[0] (init).
__global__ void __launch_bounds__(1024) k_reduce(const float* __restrict__ x,
        const int* __restrict__ Kp, const float* __restrict__ Sbp,
        Ws* __restrict__ w, float* __restrict__ out) {
    __shared__ unsigned long long sm[1024];
    __shared__ unsigned int sb[1024];
    __shared__ float red[256];
    __shared__ float red2[128];
    int t = threadIdx.x;
    int g = t >> 8;      // 0..3
    int k = t & 255;
    unsigned long long m = 0ULL;
    unsigned int bb = 0u;
    const int PP = P1 / 4;   // 32 partials per thread
    int p0 = g * PP;
    #pragma unroll 8
    for (int j = 0; j < PP; ++j) {
        unsigned long long v = w->part_packed[(p0 + j) * K_MAX + k];
        m = (v > m) ? v : m;
        unsigned int b = w->part_beta[(p0 + j) * K_MAX + k];
        bb = (b > bb) ? b : bb;
    }
    sm[t] = m;
    sb[t] = bb;
    __syncthreads();
    if (g == 0) {
        float one_minus = 0.f;
        #pragma unroll
        for (int j = 1; j < 4; ++j) {
            unsigned long long v = sm[t + 256 * j];
            m = (v > m) ? v : m;
            unsigned int b = sb[t + 256 * j];
            bb = (b > bb) ? b : bb;
        }
        int K = Kp[0];
        if (k < K) {
            float q; unsigned int idx;
            if (m == 0ULL) { q = 0.f; idx = 0u; }
            else { q = __uint_as_float((unsigned int)(m >> 32)); idx = ~(unsigned int)m; }
            w->xa_q[k] = make_float4(x[idx * 3], x[idx * 3 + 1], x[idx * 3 + 2], q);
            one_minus = 1.f - __uint_as_float(bb);
        }
        red[k] = one_minus;
    }
    __syncthreads();
    for (int s = 128; s > 0; s >>= 1) { if (t < s) red[t] += red[t + s]; __syncthreads(); }
    float sum1 = red[0];          // valid for all after final barrier
    if (t < 128) red2[t] = w->part_bg[t];
    __syncthreads();
    for (int s = 64; s > 0; s >>= 1) { if (t < s) red2[t] += red2[t + s]; __syncthreads(); }
    float bg = red2[0];
    __syncthreads();
    if (t < 128) red2[t] = w->part_nb[t];
    __syncthreads();
    for (int s = 64; s > 0; s >>= 1) { if (t < s) red2[t] += red2[t + s]; __syncthreads(); }
    if (t == 0) {
        float nb = red2[0];
        out[0] = sum1 / (float)Kp[0] + Sbp[0] / nb * bg;
    }
}

// Stage 3: N x K potential; member select hoisted out of the K loop.
__global__ void __launch_bounds__(256) k_main(const float* __restrict__ x,
        const float* __restrict__ beta, const int* __restrict__ y,
        const int* __restrict__ Kp, const float* __restrict__ qminp,
        const Ws* __restrict__ w, float* __restrict__ out, int N) {
    __shared__ float4 s_xa[K_MAX];
    __shared__ float red[256];
    int t = threadIdx.x;
    int K = Kp[0];
    if (t < K) s_xa[t] = w->xa_q[t];
    __syncthreads();
    int i = blockIdx.x * 256 + t;
    float contrib = 0.f;
    if (i < N) {
        float x0 = x[i * 3], x1 = x[i * 3 + 1], x2 = x[i * 3 + 2];
        float b = beta[i];
        int yi = y[i];
        float a = atanhf(b);
        float qi = fmaf(a, a, qminp[0]);
        float acc = 0.f;
        #pragma unroll 8
        for (int k = 0; k < K; ++k) {
            float4 aq = s_xa[k];
            float dx = x0 - aq.x, dy = x1 - aq.y, dz = x2 - aq.z;
            float d = fmaf(dx, dx, fmaf(dy, dy, dz * dz));
            acc = fmaf(fmaxf(1.f - d, 0.f), aq.w, acc);
        }
        if (yi >= 0) {   // swap repulsive term for attractive on the member cluster
            float4 aq = s_xa[yi];
            float dx = x0 - aq.x, dy = x1 - aq.y, dz = x2 - aq.z;
            float d = fmaf(dx, dx, fmaf(dy, dy, dz * dz));
            acc += (d - fmaxf(1.f - d, 0.f)) * aq.w;
        }
        contrib = acc * qi;
    }
    red[t] = contrib;
    __syncthreads();
    for (int s = 128; s > 0; s >>= 1) { if (t < s) red[t] += red[t + s]; __syncthreads(); }
    if (t == 0) atomicAdd(out, red[0] * (1.f / (float)N));
}

extern "C" void kernel_launch(void* const* d_in, const int* in_sizes, int n_in,
                              void* d_out, int out_size, void* d_ws, size_t ws_size,
                              hipStream_t stream) {
    const float* x     = (const float*)d_in[0];
    const float* beta  = (const float*)d_in[1];
    const int*   y     = (const int*)d_in[2];
    const int*   Kp    = (const int*)d_in[3];
    const float* Sbp   = (const float*)d_in[4];
    const float* qminp = (const float*)d_in[5];
    float* out = (float*)d_out;
    int N = in_sizes[1];
    Ws* w = (Ws*)d_ws;
    int nb = (N + 255) / 256;

    k_scan<<<P1, 256, 0, stream>>>(beta, y, qminp, w, N);
    k_reduce<<<1, 1024, 0, stream>>>(x, Kp, Sbp, w, out);
    k_main<<<nb, 256, 0, stream>>>(x, beta, y, Kp, qminp, w, out, N);
}